// Round 2
// baseline (493.091 us; speedup 1.0000x reference)
//
#include <hip/hip_runtime.h>
#include <hip/hip_bf16.h>
#include <stdint.h>

// Problem constants (fixed-shape problem)
#define B 512
#define N 100000
#define D 128
#define INV_T (1.0f / 0.07f)

// Masks are int32 (0/1), one per (b,n). Read as uint4 = 4 elements/thread.
#define ROW_U4 (N / 4)           // 25000 uint4 groups per mask row
#define CHUNK_U4 256             // uint4 groups per block => 1024 n-values
#define NCHUNKS ((ROW_U4 + CHUNK_U4 - 1) / CHUNK_U4)   // 98

// ---------------------------------------------------------------- normalize
__global__ void normalize_kernel(const float* __restrict__ codes,
                                 float* __restrict__ v) {
    const int b = blockIdx.x;     // 512 blocks, 64 threads
    const int t = threadIdx.x;
    float c0 = codes[b * D + t];
    float c1 = codes[b * D + t + 64];
    float s = c0 * c0 + c1 * c1;
    #pragma unroll
    for (int off = 32; off; off >>= 1) s += __shfl_xor(s, off, 64);
    float rn = 1.0f / sqrtf(s);
    v[b * D + t]      = c0 * rn;
    v[b * D + t + 64] = c1 * rn;
}

// ---------------------------------------------------------------- main scan
// Grid: (NCHUNKS, B). Block: 256 threads.
// Phase 1: scan int32 mask elements for this (row, n-chunk), enqueue set bits.
// Phase 2: wave-cooperative dot(v[b], bank[n]) per queue entry,
//          e = exp(dot/T), accumulate d1/d2, one atomic per wave per row.
__global__ void scan_kernel(const float* __restrict__ bank,
                            const float* __restrict__ v,
                            const uint32_t* __restrict__ bg,
                            const uint32_t* __restrict__ im,
                            float* __restrict__ d1,
                            float* __restrict__ d2) {
    __shared__ float vrow[D];
    __shared__ int   queue[CHUNK_U4 * 4];    // worst case: every element set
    __shared__ int   qcount;

    const int b   = blockIdx.y;
    const int tid = threadIdx.x;

    if (tid < D) vrow[tid] = v[b * D + tid];
    if (tid == 0) qcount = 0;
    __syncthreads();

    const int g = blockIdx.x * CHUNK_U4 + tid;   // uint4 index in this row
    if (g < ROW_U4) {
        const uint4* bgu = (const uint4*)(bg + (size_t)b * N);
        const uint4* imu = (const uint4*)(im + (size_t)b * N);
        uint4 a = bgu[g];
        uint4 c = imu[g];
        uint32_t aw[4] = {a.x, a.y, a.z, a.w};
        uint32_t cw[4] = {c.x, c.y, c.z, c.w};
        #pragma unroll
        for (int j = 0; j < 4; ++j) {
            uint32_t f = (aw[j] ? 1u : 0u) | (cw[j] ? 2u : 0u);
            if (f) {
                int n = g * 4 + j;
                int slot = atomicAdd(&qcount, 1);
                queue[slot] = (n << 2) | (int)f;
            }
        }
    }
    __syncthreads();

    const int cnt  = qcount;
    const int wave = tid >> 6;
    const int lane = tid & 63;
    float acc1 = 0.0f, acc2 = 0.0f;

    const float2* vr2 = (const float2*)vrow;
    const float2  vv  = vr2[lane];

    for (int i = wave; i < cnt; i += 4) {
        int ent = queue[i];
        int n   = ent >> 2;
        int f   = ent & 3;
        const float2* br = (const float2*)(bank + (size_t)n * D);
        float2 bv = br[lane];                 // 64 lanes x 8B = 512B coalesced
        float  p  = vv.x * bv.x + vv.y * bv.y;
        #pragma unroll
        for (int off = 32; off; off >>= 1) p += __shfl_xor(p, off, 64);
        float e = __expf(p * INV_T);
        if (lane == 0) {
            if (f & 1) acc1 += e;
            if (f & 2) acc2 += e;
        }
    }
    if (lane == 0) {
        if (acc1 != 0.0f) atomicAdd(&d1[b], acc1);
        if (acc2 != 0.0f) atomicAdd(&d2[b], acc2);
    }
}

// ---------------------------------------------------------------- finalize
__global__ void finalize_kernel(const float* __restrict__ d1,
                                const float* __restrict__ d2,
                                float* __restrict__ out) {
    __shared__ float red[8];
    const int t = threadIdx.x;    // 512 threads
    float val = logf(d1[t]) - logf(d2[t]);
    #pragma unroll
    for (int off = 32; off; off >>= 1) val += __shfl_xor(val, off, 64);
    if ((t & 63) == 0) red[t >> 6] = val;
    __syncthreads();
    if (t == 0) {
        float s = 0.0f;
        #pragma unroll
        for (int i = 0; i < 8; ++i) s += red[i];
        out[0] = s / (float)B;
    }
}

extern "C" void kernel_launch(void* const* d_in, const int* in_sizes, int n_in,
                              void* d_out, int out_size, void* d_ws, size_t ws_size,
                              hipStream_t stream) {
    const float*    codes = (const float*)d_in[0];
    const float*    bank  = (const float*)d_in[1];
    const uint32_t* bg    = (const uint32_t*)d_in[2];
    const uint32_t* im    = (const uint32_t*)d_in[3];
    float*          out   = (float*)d_out;

    // workspace layout: v (B*D f32), d1 (B f32), d2 (B f32)
    float* v  = (float*)d_ws;
    float* d1 = v + B * D;
    float* d2 = d1 + B;

    hipMemsetAsync(d1, 0, 2 * B * sizeof(float), stream);

    normalize_kernel<<<B, 64, 0, stream>>>(codes, v);
    scan_kernel<<<dim3(NCHUNKS, B), 256, 0, stream>>>(bank, v, bg, im, d1, d2);
    finalize_kernel<<<1, B, 0, stream>>>(d1, d2, out);
}

// Round 3
// 98.275 us; speedup vs baseline: 5.0174x; 5.0174x over previous
//
#include <hip/hip_runtime.h>
#include <hip/hip_bf16.h>
#include <stdint.h>

// Problem constants (fixed-shape problem)
#define B 512
#define N 100000
#define D 128
#define INV_T (1.0f / 0.07f)

// Masks are int32 (0/1). Read as uint4 = 4 elements (16 B) per load.
#define ROW_U4   (N / 4)         // 25000 uint4 groups per mask row
#define NBX      8               // blocks per row
#define BLK_U4   (ROW_U4 / NBX)  // 3125 uint4 groups per block (exact)
#define QCAP     2048            // queue entries (expected ~64, mean+many sigma)

// ------------------------------------------------- normalize + zero d1/d2
__global__ void normalize_kernel(const float* __restrict__ codes,
                                 float* __restrict__ v,
                                 float* __restrict__ d1,
                                 float* __restrict__ d2) {
    const int b = blockIdx.x;     // 512 blocks, 64 threads
    const int t = threadIdx.x;
    float c0 = codes[b * D + t];
    float c1 = codes[b * D + t + 64];
    float s = c0 * c0 + c1 * c1;
    #pragma unroll
    for (int off = 32; off; off >>= 1) s += __shfl_xor(s, off, 64);
    float rn = 1.0f / sqrtf(s);
    v[b * D + t]      = c0 * rn;
    v[b * D + t + 64] = c1 * rn;
    if (t == 0) { d1[b] = 0.0f; d2[b] = 0.0f; }
}

// ---------------------------------------------------------------- main scan
// Grid: (NBX, B). Block: 256 threads.
// Phase 1: stream this block's 3125-uint4 slice of both mask rows with
//          4-deep batched loads (MLP), enqueue set elements into LDS queue.
// Phase 2: half-wave (32 lanes x float4 = 512B) per bank row, 2 rows/wave/iter,
//          dot -> exp -> accumulate, one atomic per block per denominator.
__global__ void scan_kernel(const float* __restrict__ bank,
                            const float* __restrict__ v,
                            const uint32_t* __restrict__ bg,
                            const uint32_t* __restrict__ im,
                            float* __restrict__ d1,
                            float* __restrict__ d2) {
    __shared__ float vrow[D];
    __shared__ int   queue[QCAP];
    __shared__ int   qcount;

    const int b   = blockIdx.y;
    const int tid = threadIdx.x;

    if (tid < D) vrow[tid] = v[b * D + tid];
    if (tid == 0) qcount = 0;
    __syncthreads();

    const uint4* bgu = (const uint4*)(bg + (size_t)b * N);
    const uint4* imu = (const uint4*)(im + (size_t)b * N);
    const int start = blockIdx.x * BLK_U4;

    #define PROCESS(av, cv, gidx)                                          \
    {                                                                      \
        uint32_t aw[4] = {(av).x, (av).y, (av).z, (av).w};                 \
        uint32_t cw[4] = {(cv).x, (cv).y, (cv).z, (cv).w};                 \
        _Pragma("unroll")                                                  \
        for (int j = 0; j < 4; ++j) {                                      \
            uint32_t f = (aw[j] ? 1u : 0u) | (cw[j] ? 2u : 0u);            \
            if (f) {                                                       \
                int slot = atomicAdd(&qcount, 1);                          \
                if (slot < QCAP) queue[slot] = (((gidx) * 4 + j) << 2) | (int)f; \
            }                                                              \
        }                                                                  \
    }

    // 3125 = 12*256 + 53.  Three batches of 4 coalesced iterations.
    for (int k = 0; k < 3; ++k) {
        int g = start + k * 1024 + tid;
        uint4 a0 = bgu[g];
        uint4 a1 = bgu[g + 256];
        uint4 a2 = bgu[g + 512];
        uint4 a3 = bgu[g + 768];
        uint4 c0 = imu[g];
        uint4 c1 = imu[g + 256];
        uint4 c2 = imu[g + 512];
        uint4 c3 = imu[g + 768];
        PROCESS(a0, c0, g);
        PROCESS(a1, c1, g + 256);
        PROCESS(a2, c2, g + 512);
        PROCESS(a3, c3, g + 768);
    }
    if (tid < 53) {
        int g = start + 3072 + tid;
        uint4 a0 = bgu[g];
        uint4 c0 = imu[g];
        PROCESS(a0, c0, g);
    }
    #undef PROCESS
    __syncthreads();

    const int cnt  = qcount;      // expected ~64 << QCAP
    const int wave = tid >> 6;
    const int lane = tid & 63;
    const int half = lane >> 5;   // each half-wave handles one bank row
    const int l32  = lane & 31;

    float acc1 = 0.0f, acc2 = 0.0f;
    const float4* vr4 = (const float4*)vrow;
    const float4  vv  = vr4[l32];             // 32 lanes x float4 = 128 floats

    for (int base = wave * 2; base < cnt; base += 8) {
        int idx = base + half;
        float e = 0.0f;
        int   f = 0;
        if (idx < cnt) {
            int ent = queue[idx];
            int n   = ent >> 2;
            f       = ent & 3;
            const float4* br = (const float4*)(bank + (size_t)n * D);
            float4 bv = br[l32];              // 32 lanes x 16B = 512B coalesced
            float  p  = vv.x * bv.x + vv.y * bv.y + vv.z * bv.z + vv.w * bv.w;
            #pragma unroll
            for (int off = 16; off; off >>= 1) p += __shfl_xor(p, off, 64);
            e = __expf(p * INV_T);
        }
        if (l32 == 0 && f) {                  // lanes 0 and 32
            if (f & 1) acc1 += e;
            if (f & 2) acc2 += e;
        }
    }
    acc1 += __shfl_xor(acc1, 32, 64);
    acc2 += __shfl_xor(acc2, 32, 64);
    if (lane == 0) {
        if (acc1 != 0.0f) atomicAdd(&d1[b], acc1);
        if (acc2 != 0.0f) atomicAdd(&d2[b], acc2);
    }
}

// ---------------------------------------------------------------- finalize
__global__ void finalize_kernel(const float* __restrict__ d1,
                                const float* __restrict__ d2,
                                float* __restrict__ out) {
    __shared__ float red[8];
    const int t = threadIdx.x;    // 512 threads
    float val = logf(d1[t]) - logf(d2[t]);
    #pragma unroll
    for (int off = 32; off; off >>= 1) val += __shfl_xor(val, off, 64);
    if ((t & 63) == 0) red[t >> 6] = val;
    __syncthreads();
    if (t == 0) {
        float s = 0.0f;
        #pragma unroll
        for (int i = 0; i < 8; ++i) s += red[i];
        out[0] = s / (float)B;
    }
}

extern "C" void kernel_launch(void* const* d_in, const int* in_sizes, int n_in,
                              void* d_out, int out_size, void* d_ws, size_t ws_size,
                              hipStream_t stream) {
    const float*    codes = (const float*)d_in[0];
    const float*    bank  = (const float*)d_in[1];
    const uint32_t* bg    = (const uint32_t*)d_in[2];
    const uint32_t* im    = (const uint32_t*)d_in[3];
    float*          out   = (float*)d_out;

    // workspace layout: v (B*D f32), d1 (B f32), d2 (B f32)
    float* v  = (float*)d_ws;
    float* d1 = v + B * D;
    float* d2 = d1 + B;

    normalize_kernel<<<B, 64, 0, stream>>>(codes, v, d1, d2);
    scan_kernel<<<dim3(NBX, B), 256, 0, stream>>>(bank, v, bg, im, d1, d2);
    finalize_kernel<<<1, B, 0, stream>>>(d1, d2, out);
}